// Round 1
// baseline (175.325 us; speedup 1.0000x reference)
//
#include <hip/hip_runtime.h>
#include <stdint.h>
#include <stddef.h>

// ---------------------------------------------------------------------------
// FixedEmbedderNN: fused eval-mode MLP over embedded tabular features.
// Math folds (exact, fp32 precompute):
//   WL_i   = W1[i] @ W2[i]                      (128x128)   [layers are linear]
//   bfold_i= b1[i] @ W2[i] + b2[i]              (128)
//   Bnum   = rows f<20: W_num[f] @ W_in[(20+f)*32 .. ]      (21x128, row20 = b_in + b_num-part)
//   Tcat1[f][c] = emb[f][c] @ W_in[f*32..] @ WL_0 (bf16)    [GEMM-1 + layer-1 GEMM folded into table]
//   A1     = Bnum @ WL_0  (+ bfold_0 into row 20)           (21x128 fp32)
// Main kernel per row:
//   h1_pre = sum_f Tcat1[f][idx_f] + sum_f x_f*A1[f] + A1[20]
//   h1 = LN_0(h1_pre); h2 = LN_1(h1 @ WL_1 + bfold_1); out = h2 @ W_out + b_out
// GEMMs via mfma_f32_16x16x32_bf16; weights pre-packed in B-fragment order.
// ---------------------------------------------------------------------------

typedef __attribute__((ext_vector_type(8))) short short8;
typedef __attribute__((ext_vector_type(4))) float f32x4;

#define LN_EPS 1e-5f

__device__ __forceinline__ float bflo(uint32_t u){ union{uint32_t u;float f;} c; c.u = u<<16; return c.f; }
__device__ __forceinline__ float bfhi(uint32_t u){ union{uint32_t u;float f;} c; c.u = u&0xffff0000u; return c.f; }
__device__ __forceinline__ uint16_t f2bf(float f){ union{float f;uint32_t u;} c; c.f=f; return (uint16_t)((c.u + 0x7fffu + ((c.u>>16)&1u))>>16); }

// ---------------- precompute kernel 1 (no deps) ----------------
__global__ __launch_bounds__(128) void pre1(
    const float* __restrict__ W_num, const float* __restrict__ b_num,
    const float* __restrict__ W_in,  const float* __restrict__ b_in,
    const float* __restrict__ W1,    const float* __restrict__ b1,
    const float* __restrict__ W2,    const float* __restrict__ b2,
    const float* __restrict__ W_out,
    float* __restrict__ WLf,    // [2][128][128]
    float* __restrict__ Bnum,   // [21][128]
    float* __restrict__ bfold,  // [2][128]
    uint16_t* __restrict__ woutp) // 128x128 bf16 B-frag pack
{
  const int b = blockIdx.x, j = threadIdx.x;
  if (b < 256) {                       // WL = W1@W2 per layer
    const int l = b >> 7, k = b & 127;
    const float* w1r = W1 + (l*128 + k)*256;
    const float* w2  = W2 + l*256*128;
    float s = 0.f;
    for (int m = 0; m < 256; m++) s = fmaf(w1r[m], w2[m*128 + j], s);
    WLf[(l*128 + k)*128 + j] = s;
  } else if (b < 277) {                // Bnum rows (numeric fold + const base)
    const int r = b - 256;
    if (r < 20) {
      const float* wn = W_num + r*32;
      const float* wi = W_in + (size_t)(20 + r)*32*128;
      float s = 0.f;
      for (int e = 0; e < 32; e++) s = fmaf(wn[e], wi[e*128 + j], s);
      Bnum[r*128 + j] = s;
    } else {
      float s = b_in[j];
      for (int f = 0; f < 20; f++) {
        const float* bn = b_num + f*32;
        const float* wi = W_in + (size_t)(20 + f)*32*128;
        for (int e = 0; e < 32; e++) s = fmaf(bn[e], wi[e*128 + j], s);
      }
      Bnum[20*128 + j] = s;
    }
  } else if (b < 279) {                // bfold = b1@W2 + b2
    const int l = b - 277;
    const float* b1r = b1 + l*256;
    const float* w2  = W2 + l*256*128;
    float s = b2[l*128 + j];
    for (int k = 0; k < 256; k++) s = fmaf(b1r[k], w2[k*128 + j], s);
    bfold[l*128 + j] = s;
  } else {                             // W_out B-frag pack
    for (int grp = (b - 279)*128 + j; grp < 2048; grp += 1024) {
      const int lane = grp & 63, ks = (grp >> 6) & 3, nt = grp >> 8;
      const int kbase = 32*ks + 8*(lane >> 4), col = 16*nt + (lane & 15);
      for (int i = 0; i < 8; i++) woutp[grp*8 + i] = f2bf(W_out[(kbase + i)*128 + col]);
    }
  }
}

// ---------------- precompute kernel 2 (depends on pre1) ----------------
__global__ __launch_bounds__(128) void pre2(
    const float* __restrict__ emb, const float* __restrict__ W_in,
    const float* __restrict__ WLf, const float* __restrict__ Bnum,
    const float* __restrict__ bfold,
    uint16_t* __restrict__ tcat,  // [20][50][128] bf16
    float* __restrict__ A1,       // [21][128] fp32
    uint16_t* __restrict__ wl2p)  // WL_1 B-frag pack
{
  const int b = blockIdx.x, j = threadIdx.x;
  if (b < 1000) {                      // Tcat1 = emb@W_in_slice@WL_0
    __shared__ float t[128];
    const int f = b / 50, c = b % 50;
    const float* e  = emb + (f*50 + c)*32;
    const float* wi = W_in + (size_t)f*32*128;
    float s = 0.f;
    for (int k = 0; k < 32; k++) s = fmaf(e[k], wi[k*128 + j], s);
    t[j] = s;
    __syncthreads();
    float s2 = 0.f;
    for (int k = 0; k < 128; k++) s2 = fmaf(t[k], WLf[k*128 + j], s2);
    tcat[(f*50 + c)*128 + j] = f2bf(s2);
  } else if (b < 1021) {               // A1 = Bnum@WL_0 (+bfold_0 into row 20)
    const int r = b - 1000;
    float s = (r == 20) ? bfold[j] : 0.f;
    const float* br = Bnum + r*128;
    for (int k = 0; k < 128; k++) s = fmaf(br[k], WLf[k*128 + j], s);
    A1[r*128 + j] = s;
  } else {                             // WL_1 B-frag pack
    const float* wl2 = WLf + 16384;
    for (int grp = (b - 1021)*128 + j; grp < 2048; grp += 1024) {
      const int lane = grp & 63, ks = (grp >> 6) & 3, nt = grp >> 8;
      const int kbase = 32*ks + 8*(lane >> 4), col = 16*nt + (lane & 15);
      for (int i = 0; i < 8; i++) wl2p[grp*8 + i] = f2bf(wl2[(kbase + i)*128 + col]);
    }
  }
}

// ---------------- main fused kernel ----------------
// block = 256 thr (4 waves), wave = 32 rows (2 m-tiles of 16), block tile = 128 rows.
__global__ __launch_bounds__(256) void fused_main(
    const float* __restrict__ x,
    const uint16_t* __restrict__ tcat,
    const float* __restrict__ A1,
    const uint16_t* __restrict__ wl2p,
    const uint16_t* __restrict__ woutp,
    const float* __restrict__ bfold,
    const float* __restrict__ ln_g, const float* __restrict__ ln_b,
    const float* __restrict__ b_out,
    float* __restrict__ out)
{
  __shared__ float xs[128*41];                       // x tile, padded stride 41 (bank-conflict-free)
  __shared__ __align__(16) uint16_t hbuf[128*136];   // h2n roundtrip, padded stride 136
  const int tid = threadIdx.x;
  const int lane = tid & 63, w = tid >> 6;
  const int g = lane >> 4, c16 = lane & 15;
  const int base_row = blockIdx.x * 128;

  const float* xsrc = x + (size_t)base_row*40;
  for (int i = tid; i < 128*40; i += 256) xs[(i/40)*41 + (i%40)] = xsrc[i];
  __syncthreads();

  // C-layout column constants (col = c16 + 16*nt)
  float g2v[8], b2v[8], bf2[8], bov[8];
  #pragma unroll
  for (int nt = 0; nt < 8; nt++) {
    const int col = c16 + 16*nt;
    g2v[nt] = ln_g[128 + col]; b2v[nt] = ln_b[128 + col];
    bf2[nt] = bfold[128 + col]; bov[nt] = b_out[col];
  }

  for (int m = 0; m < 2; m++) {
    const int lrow = w*32 + m*16 + c16;          // this lane's row (A-layout)
    const float* xr = xs + lrow*41;

    // ---- phase A: h1_pre in A-layout (lane: row=c16, cols = 32ks+8g+i) ----
    float acc[4][8];
    #pragma unroll
    for (int ks = 0; ks < 4; ks++) {
      const float* ab = A1 + 20*128 + 32*ks + 8*g;   // constant row (base+bias fold)
      #pragma unroll
      for (int i = 0; i < 8; i++) acc[ks][i] = ab[i];
    }
    for (int f = 0; f < 20; f++) {
      const int idx = (int)xr[f];
      const float xv = xr[20 + f];
      const uint16_t* trow = tcat + (f*50 + idx)*128;
      const float* arow = A1 + f*128;
      #pragma unroll
      for (int ks = 0; ks < 4; ks++) {
        const int colb = 32*ks + 8*g;
        const uint4 t = *reinterpret_cast<const uint4*>(trow + colb);
        acc[ks][0] += bflo(t.x); acc[ks][1] += bfhi(t.x);
        acc[ks][2] += bflo(t.y); acc[ks][3] += bfhi(t.y);
        acc[ks][4] += bflo(t.z); acc[ks][5] += bfhi(t.z);
        const float* ab = arow + colb;
        acc[ks][6] += bflo(t.w); acc[ks][7] += bfhi(t.w);
        #pragma unroll
        for (int i = 0; i < 8; i++) acc[ks][i] = fmaf(xv, ab[i], acc[ks][i]);
      }
    }

    // ---- LN_0 over A-layout (row owned by 4 lanes: xor 16,32) ----
    float s = 0.f;
    #pragma unroll
    for (int ks = 0; ks < 4; ks++)
      #pragma unroll
      for (int i = 0; i < 8; i++) s += acc[ks][i];
    s += __shfl_xor(s, 16); s += __shfl_xor(s, 32);
    const float mu = s * (1.f/128.f);
    float q = 0.f;
    #pragma unroll
    for (int ks = 0; ks < 4; ks++)
      #pragma unroll
      for (int i = 0; i < 8; i++) { const float d = acc[ks][i] - mu; q = fmaf(d, d, q); }
    q += __shfl_xor(q, 16); q += __shfl_xor(q, 32);
    const float rs = rsqrtf(q*(1.f/128.f) + LN_EPS);

    short8 a2[4];
    #pragma unroll
    for (int ks = 0; ks < 4; ks++) {
      const int colb = 32*ks + 8*g;
      const float* gg = ln_g + colb;
      const float* bb = ln_b + colb;
      #pragma unroll
      for (int i = 0; i < 8; i++) {
        const float rg = rs*gg[i];
        a2[ks][i] = (short)f2bf(fmaf(acc[ks][i] - mu, rg, bb[i]));
      }
    }

    // ---- layer-2 fold GEMM: acc2 = h1n @ WL_1 (C-layout out) ----
    f32x4 acc2[8];
    #pragma unroll
    for (int nt = 0; nt < 8; nt++) acc2[nt] = (f32x4){0.f,0.f,0.f,0.f};
    #pragma unroll
    for (int ks = 0; ks < 4; ks++)
      #pragma unroll
      for (int nt = 0; nt < 8; nt++) {
        const short8 bfr = *reinterpret_cast<const short8*>(wl2p + ((nt*4 + ks)*64 + lane)*8);
        acc2[nt] = __builtin_amdgcn_mfma_f32_16x16x32_bf16(a2[ks], bfr, acc2[nt], 0, 0, 0);
      }

    // ---- +bias, LN_1 (C-layout: row owned by 16 lanes: xor 1,2,4,8), write bf16 to LDS ----
    #pragma unroll
    for (int r = 0; r < 4; r++) {
      float sr = 0.f;
      #pragma unroll
      for (int nt = 0; nt < 8; nt++) { acc2[nt][r] += bf2[nt]; sr += acc2[nt][r]; }
      sr += __shfl_xor(sr, 1); sr += __shfl_xor(sr, 2); sr += __shfl_xor(sr, 4); sr += __shfl_xor(sr, 8);
      const float mu2 = sr * (1.f/128.f);
      float qr = 0.f;
      #pragma unroll
      for (int nt = 0; nt < 8; nt++) { const float d = acc2[nt][r] - mu2; qr = fmaf(d, d, qr); }
      qr += __shfl_xor(qr, 1); qr += __shfl_xor(qr, 2); qr += __shfl_xor(qr, 4); qr += __shfl_xor(qr, 8);
      const float rs2 = rsqrtf(qr*(1.f/128.f) + LN_EPS);
      const int row = w*32 + m*16 + 4*g + r;
      #pragma unroll
      for (int nt = 0; nt < 8; nt++) {
        const float rg = rs2*g2v[nt];
        hbuf[row*136 + c16 + 16*nt] = f2bf(fmaf(acc2[nt][r] - mu2, rg, b2v[nt]));
      }
    }

    // ---- C->A layout via LDS (same-wave DS ops are in-order) ----
    short8 a3[4];
    const int arow = (w*32 + m*16 + c16)*136;
    #pragma unroll
    for (int ks = 0; ks < 4; ks++)
      a3[ks] = *reinterpret_cast<const short8*>(&hbuf[arow + 32*ks + 8*g]);

    // ---- output GEMM: acc3 = h2n @ W_out ----
    f32x4 acc3[8];
    #pragma unroll
    for (int nt = 0; nt < 8; nt++) acc3[nt] = (f32x4){0.f,0.f,0.f,0.f};
    #pragma unroll
    for (int ks = 0; ks < 4; ks++)
      #pragma unroll
      for (int nt = 0; nt < 8; nt++) {
        const short8 bfr = *reinterpret_cast<const short8*>(woutp + ((nt*4 + ks)*64 + lane)*8);
        acc3[nt] = __builtin_amdgcn_mfma_f32_16x16x32_bf16(a3[ks], bfr, acc3[nt], 0, 0, 0);
      }

    // ---- store (C-layout; 16 consecutive cols per 16-lane group = 64B segments) ----
    float* orow = out + ((size_t)base_row + w*32 + m*16 + 4*g)*128;
    #pragma unroll
    for (int nt = 0; nt < 8; nt++)
      #pragma unroll
      for (int r = 0; r < 4; r++)
        orow[r*128 + c16 + 16*nt] = acc3[nt][r] + bov[nt];
  }
}

// ---------------- launcher ----------------
extern "C" void kernel_launch(void* const* d_in, const int* in_sizes, int n_in,
                              void* d_out, int out_size, void* d_ws, size_t ws_size,
                              hipStream_t stream)
{
  const float* x     = (const float*)d_in[0];
  const float* emb   = (const float*)d_in[1];
  const float* W_num = (const float*)d_in[2];
  const float* b_num = (const float*)d_in[3];
  const float* W_in  = (const float*)d_in[4];
  const float* b_in  = (const float*)d_in[5];
  const float* W1    = (const float*)d_in[6];
  const float* b1    = (const float*)d_in[7];
  const float* W2    = (const float*)d_in[8];
  const float* b2    = (const float*)d_in[9];
  const float* ln_g  = (const float*)d_in[10];
  const float* ln_b  = (const float*)d_in[11];
  const float* W_out = (const float*)d_in[12];
  const float* b_out = (const float*)d_in[13];
  float* out = (float*)d_out;

  char* ws = (char*)d_ws;
  float*    WLf   = (float*)(ws + 0);       // 2*128*128 f32   = 131072 B
  float*    Bnum  = (float*)(ws + 131072);  // 21*128 f32      =  10752 B
  float*    bfold = (float*)(ws + 141824);  // 2*128 f32       =   1024 B
  float*    A1    = (float*)(ws + 142848);  // 21*128 f32      =  10752 B
  uint16_t* tcat  = (uint16_t*)(ws + 153600); // 20*50*128 bf16 = 256000 B
  uint16_t* wl2p  = (uint16_t*)(ws + 409600); // 16384 bf16     =  32768 B
  uint16_t* woutp = (uint16_t*)(ws + 442368); // 16384 bf16     =  32768 B

  const int nrows = in_sizes[0] / 40;       // 98304
  const int grid  = nrows / 128;            // 768

  pre1<<<dim3(287), dim3(128), 0, stream>>>(W_num, b_num, W_in, b_in, W1, b1, W2, b2, W_out,
                                            WLf, Bnum, bfold, woutp);
  pre2<<<dim3(1029), dim3(128), 0, stream>>>(emb, W_in, WLf, Bnum, bfold, tcat, A1, wl2p);
  fused_main<<<dim3(grid), dim3(256), 0, stream>>>(x, tcat, A1, wl2p, woutp, bfold,
                                                   ln_g, ln_b, b_out, out);
}

// Round 2
// 107.803 us; speedup vs baseline: 1.6263x; 1.6263x over previous
//
#include <hip/hip_runtime.h>
#include <hip/hip_bf16.h>
#include <stdint.h>
#include <stddef.h>

// ---------------------------------------------------------------------------
// FixedEmbedderNN — all-linear fold + transposed-MFMA pipeline.
//   WL_i   = W1[i]@W2[i];  bfold_i = b1[i]@W2[i]+b2[i]
//   Tcat1[f][c] = emb[f][c] @ W_in_f @ WL_0      (bf16, column-PERMUTED store)
//   A1[k][:]    = numeric fold rows (k=0..19), k=20 = const base (+bfold_0)
//   LN gamma/beta folded into downstream weights:
//     WL1' = diag(g0)@WL_1, bf1' = b0@WL_1+bfold_1
//     Wout' = diag(g1)@W_out, bout' = b1n@W_out+b_out
// Main kernel, per wave = 16 rows, everything in "lane owns row c16" layout:
//   acc = mfma(A1^T-pack, x-frag)  [numeric via matrix core]
//   acc += 20 gathered tcat rows   [contiguous 64B per lane, permuted table]
//   z1 = (acc-mu)*rs  -> LDS -> GEMM2' (transposed) -> +bf1' -> z2 -> LDS
//   -> GEMM3' (transposed) -> +bout' -> dwordx4 stores
// ---------------------------------------------------------------------------

typedef __attribute__((ext_vector_type(8))) short short8;
typedef __attribute__((ext_vector_type(4))) float f32x4;
typedef __attribute__((ext_vector_type(2))) uint32_t uint32x2;

#define LN_EPS 1e-5f

__device__ __forceinline__ float bflo(uint32_t u){ union{uint32_t u;float f;} c; c.u = u<<16; return c.f; }
__device__ __forceinline__ float bfhi(uint32_t u){ union{uint32_t u;float f;} c; c.u = u&0xffff0000u; return c.f; }
__device__ __forceinline__ uint16_t f2bf(float f){
  union{ __hip_bfloat16 h; uint16_t u; } c; c.h = __float2bfloat16(f); return c.u;
}
__device__ __forceinline__ uint32_t pkbf(float lo, float hi){
  return (uint32_t)f2bf(lo) | ((uint32_t)f2bf(hi)<<16);
}

// ---------------- precompute kernel 1 (no deps) ----------------
__global__ __launch_bounds__(128) void pre1(
    const float* __restrict__ W_num, const float* __restrict__ b_num,
    const float* __restrict__ W_in,  const float* __restrict__ b_in,
    const float* __restrict__ W1,    const float* __restrict__ b1,
    const float* __restrict__ W2,    const float* __restrict__ b2,
    const float* __restrict__ W_out, const float* __restrict__ b_out,
    const float* __restrict__ ln_g,  const float* __restrict__ ln_b,
    float* __restrict__ WLf,    // [2][128][128]
    float* __restrict__ Bnum,   // [21][128]
    float* __restrict__ bfold,  // [2][128]
    uint16_t* __restrict__ woutp, // Wout' transposed pack [(t*4+ks)*64+lane][8]
    float* __restrict__ boutp)    // bout' permuted [g*32+t*4+r]
{
  const int b = blockIdx.x, j = threadIdx.x;
  if (b < 256) {                       // WL = W1@W2 per layer
    const int l = b >> 7, k = b & 127;
    const float* w1r = W1 + (l*128 + k)*256;
    const float* w2  = W2 + l*256*128;
    float s = 0.f;
    for (int m = 0; m < 256; m++) s = fmaf(w1r[m], w2[m*128 + j], s);
    WLf[(l*128 + k)*128 + j] = s;
  } else if (b < 277) {                // Bnum rows
    const int r = b - 256;
    if (r < 20) {
      const float* wn = W_num + r*32;
      const float* wi = W_in + (size_t)(20 + r)*32*128;
      float s = 0.f;
      for (int e = 0; e < 32; e++) s = fmaf(wn[e], wi[e*128 + j], s);
      Bnum[r*128 + j] = s;
    } else {
      float s = b_in[j];
      for (int f = 0; f < 20; f++) {
        const float* bn = b_num + f*32;
        const float* wi = W_in + (size_t)(20 + f)*32*128;
        for (int e = 0; e < 32; e++) s = fmaf(bn[e], wi[e*128 + j], s);
      }
      Bnum[20*128 + j] = s;
    }
  } else if (b < 279) {                // bfold = b1@W2 + b2
    const int l = b - 277;
    const float* b1r = b1 + l*256;
    const float* w2  = W2 + l*256*128;
    float s = b2[l*128 + j];
    for (int k = 0; k < 256; k++) s = fmaf(b1r[k], w2[k*128 + j], s);
    bfold[l*128 + j] = s;
  } else if (b < 311) {                // woutp: Wout' = diag(g1)@W_out, transposed A-pack
    const int p = b - 279, t = p >> 2, ks = p & 3;
    const int lane = j & 63, rep = j >> 6;
    const int col = 16*t + (lane & 15);
    for (int ii = 0; ii < 4; ii++) {
      const int i = rep*4 + ii;
      const int k = 32*ks + 8*(lane >> 4) + i;
      woutp[((t*4 + ks)*64 + lane)*8 + i] = f2bf(ln_g[128 + k] * W_out[k*128 + col]);
    }
  } else {                             // boutp (permuted): b1n@W_out + b_out
    const int t = (j >> 2) & 7, g = j >> 5, r = j & 3;
    const int col = 16*t + 4*g + r;
    float s = b_out[col];
    for (int k = 0; k < 128; k++) s = fmaf(ln_b[128 + k], W_out[k*128 + col], s);
    boutp[j] = s;
  }
}

// ---------------- precompute kernel 2 (depends on pre1) ----------------
__global__ __launch_bounds__(128) void pre2(
    const float* __restrict__ emb, const float* __restrict__ W_in,
    const float* __restrict__ ln_g, const float* __restrict__ ln_b,
    const float* __restrict__ WLf, const float* __restrict__ Bnum,
    const float* __restrict__ bfold,
    uint16_t* __restrict__ tcatp, // [20][50][128] bf16, columns permuted g*32+t*4+r <- 16t+4g+r
    uint16_t* __restrict__ wl2p,  // WL1' transposed pack
    float* __restrict__ bf1p,     // bf1' permuted
    uint16_t* __restrict__ a1p)   // A1^T A-frag pack [t*64+lane][8]
{
  const int b = blockIdx.x, j = threadIdx.x;
  __shared__ float sh[128];
  if (b < 1000) {                      // Tcat1 = emb@W_in_slice@WL_0, permuted store
    const int f = b / 50, c = b % 50;
    const float* e  = emb + (f*50 + c)*32;
    const float* wi = W_in + (size_t)f*32*128;
    float s = 0.f;
    for (int k = 0; k < 32; k++) s = fmaf(e[k], wi[k*128 + j], s);
    sh[j] = s;
    __syncthreads();
    float s2 = 0.f;
    for (int k = 0; k < 128; k++) s2 = fmaf(sh[k], WLf[k*128 + j], s2);
    const int t = j >> 4, g = (j >> 2) & 3, r = j & 3;   // j = 16t+4g+r
    tcatp[(f*50 + c)*128 + g*32 + t*4 + r] = f2bf(s2);
  } else if (b < 1032) {               // wl2p: WL1' = diag(g0)@WL_1, transposed A-pack
    const int p = b - 1000, t = p >> 2, ks = p & 3;
    const int lane = j & 63, rep = j >> 6;
    const int col = 16*t + (lane & 15);
    const float* wl1 = WLf + 16384;
    for (int ii = 0; ii < 4; ii++) {
      const int i = rep*4 + ii;
      const int k = 32*ks + 8*(lane >> 4) + i;
      wl2p[((t*4 + ks)*64 + lane)*8 + i] = f2bf(ln_g[k] * wl1[k*128 + col]);
    }
  } else if (b == 1032) {              // bf1p (permuted): b0@WL_1 + bfold_1
    const int t = (j >> 2) & 7, g = j >> 5, r = j & 3;
    const int col = 16*t + 4*g + r;
    const float* wl1 = WLf + 16384;
    float s = bfold[128 + col];
    for (int k = 0; k < 128; k++) s = fmaf(ln_b[k], wl1[k*128 + col], s);
    bf1p[j] = s;
  } else {                             // a1p: A1[k][col] = Bnum[k]@WL_0 (+bfold0 @k==20)
    const int t = b - 1033;
    const int lane = j & 63, rep = j >> 6;
    const int col = 16*t + (lane & 15);
    for (int ii = 0; ii < 4; ii++) {
      const int i = rep*4 + ii;
      const int k = 8*(lane >> 4) + i;
      float v = 0.f;
      if (k <= 20) {
        if (k == 20) v = bfold[col];
        for (int m = 0; m < 128; m++) v = fmaf(Bnum[k*128 + m], WLf[m*128 + col], v);
      }
      a1p[(t*64 + lane)*8 + i] = f2bf(v);
    }
  }
}

// ---------------- main fused kernel ----------------
// block = 256 thr (4 waves); wave owns 16 rows; block tile = 64 rows.
__global__ __launch_bounds__(256, 4) void fused_main(
    const float* __restrict__ x,
    const uint16_t* __restrict__ tcatp,
    const uint16_t* __restrict__ a1p,
    const uint16_t* __restrict__ wl2p,
    const uint16_t* __restrict__ woutp,
    const float* __restrict__ bf1p,
    const float* __restrict__ boutp,
    float* __restrict__ out)
{
  __shared__ float xs[64*41];                        // x tile (stride 41: conflict-free)
  __shared__ __align__(16) uint16_t hbuf[4*16*136];  // per-wave 16x128 bf16, stride 136
  const int tid = threadIdx.x, lane = tid & 63, w = tid >> 6;
  const int g = lane >> 4, c16 = lane & 15;

  // stage x tile (coalesced)
  const float* xsrc = x + (size_t)blockIdx.x*64*40;
  for (int i = tid; i < 64*40; i += 256) xs[(i/40)*41 + (i%40)] = xsrc[i];
  __syncthreads();

  const float* xr = xs + (w*16 + c16)*41;        // this lane's row
  uint16_t* hb = hbuf + w*16*136;                // per-wave private

  // ---- numeric part via MFMA: acc[t] (lane owns row c16, cols 16t+4g+r) ----
  short8 xf;
  #pragma unroll
  for (int i = 0; i < 8; i++) {
    const int k = 8*g + i;
    float v = (k < 20) ? xr[20 + k] : (k == 20 ? 1.0f : 0.0f);
    ((uint16_t*)&xf)[i] = f2bf(v);               // ints<50 + {0,1}: exact in bf16
  }
  f32x4 acc[8];
  #pragma unroll
  for (int t = 0; t < 8; t++) {
    const short8 af = *reinterpret_cast<const short8*>(a1p + (t*64 + lane)*8);
    acc[t] = __builtin_amdgcn_mfma_f32_16x16x32_bf16(af, xf, (f32x4){0.f,0.f,0.f,0.f}, 0, 0, 0);
  }

  // ---- categorical gather: 20 x contiguous 64B per lane (permuted table) ----
  const uint16_t* tb = tcatp + g*32;
  #pragma unroll 2
  for (int f = 0; f < 20; f++) {
    const int idx = (int)xr[f];
    const uint4* p = reinterpret_cast<const uint4*>(tb + (f*50 + idx)*128);
    #pragma unroll
    for (int q = 0; q < 4; q++) {
      const uint4 u = p[q];
      const uint32_t wd[4] = {u.x, u.y, u.z, u.w};
      #pragma unroll
      for (int k = 0; k < 4; k++) {
        const int t = 2*q + (k >> 1), r = (k & 1)*2;
        acc[t][r]   += bflo(wd[k]);
        acc[t][r+1] += bfhi(wd[k]);
      }
    }
  }

  // ---- LN_0 (gamma/beta folded downstream): z1 = (acc-mu)*rs ----
  float s = 0.f;
  #pragma unroll
  for (int t = 0; t < 8; t++) { s += acc[t][0]+acc[t][1]+acc[t][2]+acc[t][3]; }
  s += __shfl_xor(s, 16); s += __shfl_xor(s, 32);
  const float mu = s * (1.f/128.f);
  float qv = 0.f;
  #pragma unroll
  for (int t = 0; t < 8; t++)
    #pragma unroll
    for (int r = 0; r < 4; r++) { const float d = acc[t][r]-mu; qv = fmaf(d, d, qv); }
  qv += __shfl_xor(qv, 16); qv += __shfl_xor(qv, 32);
  const float rs = rsqrtf(qv*(1.f/128.f) + LN_EPS);

  #pragma unroll
  for (int t = 0; t < 8; t++) {
    const uint32x2 v = { pkbf((acc[t][0]-mu)*rs, (acc[t][1]-mu)*rs),
                         pkbf((acc[t][2]-mu)*rs, (acc[t][3]-mu)*rs) };
    *reinterpret_cast<uint32x2*>(hb + c16*136 + 16*t + 4*g) = v;
  }
  asm volatile("s_waitcnt lgkmcnt(0)" ::: "memory");

  // ---- GEMM2' (transposed): acc2 = z1 @ WL1' ----
  short8 a2[4];
  #pragma unroll
  for (int ks = 0; ks < 4; ks++)
    a2[ks] = *reinterpret_cast<const short8*>(hb + c16*136 + 32*ks + 8*g);
  f32x4 acc2[8];
  #pragma unroll
  for (int t = 0; t < 8; t++) {
    acc2[t] = *reinterpret_cast<const f32x4*>(bf1p + g*32 + t*4);  // bias as C-init
    #pragma unroll
    for (int ks = 0; ks < 4; ks++) {
      const short8 wf = *reinterpret_cast<const short8*>(wl2p + ((t*4 + ks)*64 + lane)*8);
      acc2[t] = __builtin_amdgcn_mfma_f32_16x16x32_bf16(wf, a2[ks], acc2[t], 0, 0, 0);
    }
  }

  // ---- LN_1: z2 = (acc2-mu2)*rs2 ----
  float s2 = 0.f;
  #pragma unroll
  for (int t = 0; t < 8; t++) { s2 += acc2[t][0]+acc2[t][1]+acc2[t][2]+acc2[t][3]; }
  s2 += __shfl_xor(s2, 16); s2 += __shfl_xor(s2, 32);
  const float mu2 = s2 * (1.f/128.f);
  float q2 = 0.f;
  #pragma unroll
  for (int t = 0; t < 8; t++)
    #pragma unroll
    for (int r = 0; r < 4; r++) { const float d = acc2[t][r]-mu2; q2 = fmaf(d, d, q2); }
  q2 += __shfl_xor(q2, 16); q2 += __shfl_xor(q2, 32);
  const float rs2 = rsqrtf(q2*(1.f/128.f) + LN_EPS);

  asm volatile("s_waitcnt lgkmcnt(0)" ::: "memory");   // a2 reads done before overwrite
  #pragma unroll
  for (int t = 0; t < 8; t++) {
    const uint32x2 v = { pkbf((acc2[t][0]-mu2)*rs2, (acc2[t][1]-mu2)*rs2),
                         pkbf((acc2[t][2]-mu2)*rs2, (acc2[t][3]-mu2)*rs2) };
    *reinterpret_cast<uint32x2*>(hb + c16*136 + 16*t + 4*g) = v;
  }
  asm volatile("s_waitcnt lgkmcnt(0)" ::: "memory");

  // ---- GEMM3' (transposed): out = z2 @ Wout' + bout' ----
  short8 a3[4];
  #pragma unroll
  for (int ks = 0; ks < 4; ks++)
    a3[ks] = *reinterpret_cast<const short8*>(hb + c16*136 + 32*ks + 8*g);
  const size_t orow = ((size_t)blockIdx.x*64 + w*16 + c16)*128;
  #pragma unroll
  for (int t = 0; t < 8; t++) {
    f32x4 a3c = *reinterpret_cast<const f32x4*>(boutp + g*32 + t*4);  // bias as C-init
    #pragma unroll
    for (int ks = 0; ks < 4; ks++) {
      const short8 wf = *reinterpret_cast<const short8*>(woutp + ((t*4 + ks)*64 + lane)*8);
      a3c = __builtin_amdgcn_mfma_f32_16x16x32_bf16(wf, a3[ks], a3c, 0, 0, 0);
    }
    __builtin_nontemporal_store(a3c, reinterpret_cast<f32x4*>(out + orow + 16*t + 4*g));
  }
}

// ---------------- launcher ----------------
extern "C" void kernel_launch(void* const* d_in, const int* in_sizes, int n_in,
                              void* d_out, int out_size, void* d_ws, size_t ws_size,
                              hipStream_t stream)
{
  const float* x     = (const float*)d_in[0];
  const float* emb   = (const float*)d_in[1];
  const float* W_num = (const float*)d_in[2];
  const float* b_num = (const float*)d_in[3];
  const float* W_in  = (const float*)d_in[4];
  const float* b_in  = (const float*)d_in[5];
  const float* W1    = (const float*)d_in[6];
  const float* b1    = (const float*)d_in[7];
  const float* W2    = (const float*)d_in[8];
  const float* b2    = (const float*)d_in[9];
  const float* ln_g  = (const float*)d_in[10];
  const float* ln_b  = (const float*)d_in[11];
  const float* W_out = (const float*)d_in[12];
  const float* b_out = (const float*)d_in[13];
  float* out = (float*)d_out;

  char* ws = (char*)d_ws;
  float*    WLf   = (float*)(ws + 0);         // 131072 B
  float*    Bnum  = (float*)(ws + 131072);    //  10752 B
  float*    bfold = (float*)(ws + 141824);    //   1024 B
  uint16_t* tcatp = (uint16_t*)(ws + 142848); // 256000 B
  uint16_t* wl2p  = (uint16_t*)(ws + 398848); //  32768 B
  uint16_t* woutp = (uint16_t*)(ws + 431616); //  32768 B
  uint16_t* a1p   = (uint16_t*)(ws + 464384); //   8192 B
  float*    bf1p  = (float*)(ws + 472576);    //    512 B
  float*    boutp = (float*)(ws + 473088);    //    512 B

  const int nrows = in_sizes[0] / 40;         // 98304
  const int grid  = nrows / 64;               // 1536

  pre1<<<dim3(312), dim3(128), 0, stream>>>(W_num, b_num, W_in, b_in, W1, b1, W2, b2,
                                            W_out, b_out, ln_g, ln_b,
                                            WLf, Bnum, bfold, woutp, boutp);
  pre2<<<dim3(1041), dim3(128), 0, stream>>>(emb, W_in, ln_g, ln_b, WLf, Bnum, bfold,
                                             tcatp, wl2p, bf1p, a1p);
  fused_main<<<dim3(grid), dim3(256), 0, stream>>>(x, tcatp, a1p, wl2p, woutp,
                                                   bf1p, boutp, out);
}